// Round 2
// baseline (1038.703 us; speedup 1.0000x reference)
//
#include <hip/hip_runtime.h>
#include <hip/hip_bf16.h>

#define N 8192
#define IN_DIM 512
#define OUT_DIM 64
#define ALPHA 0.2f
#define RPW 4   // rows per wave in k_attn

typedef __hip_bfloat16 bf16;

__device__ __forceinline__ float u2f(unsigned short u) {
    union { unsigned int i; float f; } c; c.i = ((unsigned int)u) << 16; return c.f;
}

// ---------- dtype sniffer: flag=1 if float inputs are bf16, 0 if fp32 ----------
// bf16 data: even-indexed u16s are real bf16 values (plausible magnitudes).
// fp32 data: even-indexed u16s are fp32 low-mantissa garbage (~21% plausible).
__global__ void k_sniff(const unsigned short* __restrict__ feat_u16, int* __restrict__ flag) {
    int lane = threadIdx.x;  // 64 threads, 1 wave
    float v = u2f(feat_u16[2 * lane]);
    float av = fabsf(v);
    int ok = (v == 0.f) || (av > 1e-8f && av < 1e8f);  // NaN/inf fail both
    unsigned long long m = __ballot(ok);
    if (lane == 0) *flag = (__popcll(m) >= 48) ? 1 : 0;
}

// ---------- Kernel A: h = feat @ W ; h1 = h@a1 ; h2 = h@a2 ----------
__global__ __launch_bounds__(256) void k_h(const void* __restrict__ featv,
                                           const void* __restrict__ Wv,
                                           const void* __restrict__ av,
                                           const int* __restrict__ flag,
                                           float* __restrict__ h,
                                           float* __restrict__ h1,
                                           float* __restrict__ h2) {
    int wave = threadIdx.x >> 6;
    int lane = threadIdx.x & 63;
    int row = blockIdx.x * 4 + wave;
    int isbf = *flag;
    float acc = 0.f;
    float a1, a2;
    if (isbf) {
        const bf16* frow = (const bf16*)featv + (size_t)row * IN_DIM;
        const bf16* W = (const bf16*)Wv;
#pragma unroll 8
        for (int k = 0; k < IN_DIM; ++k)
            acc += __bfloat162float(frow[k]) * __bfloat162float(W[k * OUT_DIM + lane]);
        a1 = __bfloat162float(((const bf16*)av)[lane]);
        a2 = __bfloat162float(((const bf16*)av)[OUT_DIM + lane]);
    } else {
        const float* frow = (const float*)featv + (size_t)row * IN_DIM;
        const float* W = (const float*)Wv;
#pragma unroll 8
        for (int k = 0; k < IN_DIM; ++k)
            acc += frow[k] * W[k * OUT_DIM + lane];
        a1 = ((const float*)av)[lane];
        a2 = ((const float*)av)[OUT_DIM + lane];
    }
    h[(size_t)row * OUT_DIM + lane] = acc;
    float s1 = acc * a1, s2 = acc * a2;
#pragma unroll
    for (int off = 32; off; off >>= 1) {
        s1 += __shfl_xor(s1, off);
        s2 += __shfl_xor(s2, off);
    }
    if (lane == 0) { h1[row] = s1; h2[row] = s2; }
}

// ---------- Kernel B: online-softmax masked attention, acc = P @ h ----------
// Each wave owns RPW full rows (no cross-wave merging, no atomics).
// Phase A (lane=j): chunk weights + running max/rescale; Phase B (lane=c): FMA.
__global__ __launch_bounds__(256) void k_attn(const int* __restrict__ adj,
                                              const float* __restrict__ h,
                                              const float* __restrict__ h1,
                                              const float* __restrict__ h2,
                                              float* __restrict__ accbuf,
                                              float* __restrict__ lbuf) {
    __shared__ float w_lds[4][64][RPW + 1];   // +1 pad: stride-5 conflict-free writes
    __shared__ float alpha_lds[4][RPW];
    int wave = threadIdx.x >> 6;
    int lane = threadIdx.x & 63;
    int i0 = (blockIdx.x * 4 + wave) * RPW;

    float h1r[RPW], m[RPW], lacc[RPW], acc[RPW];
#pragma unroll
    for (int r = 0; r < RPW; ++r) {
        h1r[r] = h1[i0 + r];
        m[r] = -3e38f; lacc[r] = 0.f; acc[r] = 0.f;
    }

    for (int j0 = 0; j0 < N; j0 += 64) {
        int j = j0 + lane;
        float h2v = h2[j];
#pragma unroll
        for (int r = 0; r < RPW; ++r) {
            int adjv = adj[(size_t)(i0 + r) * N + j];
            float s = h1r[r] + h2v;
            s = fmaxf(s, ALPHA * s);                 // LeakyReLU (monotone)
            float sm = adjv > 0 ? s : -3e38f;
            float cm = sm;                           // chunk max over 64 lanes
#pragma unroll
            for (int off = 32; off; off >>= 1) cm = fmaxf(cm, __shfl_xor(cm, off));
            float mn = fmaxf(m[r], cm);
            float al = __expf(m[r] - mn);            // ==1 when unchanged; ==0 from -3e38
            float wv = adjv > 0 ? __expf(s - mn) : 0.f;  // s-mn <= 0, no overflow
            lacc[r] = lacc[r] * al + wv;
            m[r] = mn;
            w_lds[wave][lane][r] = wv;
            if (lane == 0) alpha_lds[wave][r] = al;
        }
        __syncthreads();
        float alr[RPW];
#pragma unroll
        for (int r = 0; r < RPW; ++r) { alr[r] = alpha_lds[wave][r]; acc[r] *= alr[r]; }
        const float* hc = h + (size_t)j0 * OUT_DIM + lane;
#pragma unroll 8
        for (int jj = 0; jj < 64; ++jj) {
            float hv = hc[(size_t)jj * OUT_DIM];
#pragma unroll
            for (int r = 0; r < RPW; ++r) acc[r] += w_lds[wave][jj][r] * hv;
        }
        __syncthreads();
    }

#pragma unroll
    for (int r = 0; r < RPW; ++r) {
        accbuf[(size_t)(i0 + r) * OUT_DIM + lane] = acc[r];
        float lv = lacc[r];
#pragma unroll
        for (int off = 32; off; off >>= 1) lv += __shfl_xor(lv, off);
        if (lane == 0) lbuf[i0 + r] = lv;
    }
}

// ---------- Kernel C: out = elu(acc / l), dtype per flag ----------
__global__ __launch_bounds__(256) void k_out(const float* __restrict__ accbuf,
                                             const float* __restrict__ lbuf,
                                             const int* __restrict__ flag,
                                             void* __restrict__ outv) {
    int idx = blockIdx.x * 256 + threadIdx.x;
    int i = idx >> 6;
    float l = lbuf[i];
    float v = l > 0.f ? accbuf[idx] / l : 0.f;
    v = v > 0.f ? v : __expf(v) - 1.f;               // ELU
    if (*flag) ((bf16*)outv)[idx] = __float2bfloat16(v);
    else       ((float*)outv)[idx] = v;
}

extern "C" void kernel_launch(void* const* d_in, const int* in_sizes, int n_in,
                              void* d_out, int out_size, void* d_ws, size_t ws_size,
                              hipStream_t stream) {
    const void* feat = d_in[0];
    const int* adj = (const int*)d_in[1];
    const void* W = d_in[2];
    const void* a = d_in[3];

    char* ws = (char*)d_ws;
    int*   flag   = (int*)(ws);
    float* h1     = (float*)(ws + 4096);
    float* h2     = (float*)(ws + 36864);
    float* h      = (float*)(ws + 69632);      // 2 MB
    float* accbuf = (float*)(ws + 2166784);    // 2 MB
    float* lbuf   = (float*)(ws + 4263936);    // 32 KB

    hipLaunchKernelGGL(k_sniff, dim3(1), dim3(64), 0, stream,
                       (const unsigned short*)feat, flag);
    hipLaunchKernelGGL(k_h, dim3(N / 4), dim3(256), 0, stream,
                       feat, W, a, flag, h, h1, h2);
    hipLaunchKernelGGL(k_attn, dim3(N / (RPW * 4)), dim3(256), 0, stream,
                       adj, h, h1, h2, accbuf, lbuf);
    hipLaunchKernelGGL(k_out, dim3((N * OUT_DIM) / 256), dim3(256), 0, stream,
                       accbuf, lbuf, flag, d_out);
}